// Round 1
// baseline (5839.476 us; speedup 1.0000x reference)
//
#include <hip/hip_runtime.h>

#define N_NODES 50000
#define N_EDGES 1600000
#define D_IN 128
#define D_HID 256

// ---------------------------------------------------------------------------
// deg[i] = # edges with dst == i   (self-loop added later as +1)
__global__ __launch_bounds__(256) void deg_kernel(const int* __restrict__ dst,
                                                  int* __restrict__ deg, int E) {
    int i = blockIdx.x * blockDim.x + threadIdx.x;
    int stride = gridDim.x * blockDim.x;
    for (; i < E; i += stride) atomicAdd(&deg[dst[i]], 1);
}

// dinv[i] = rsqrt(deg[i] + 1)
__global__ __launch_bounds__(256) void dinv_kernel(const int* __restrict__ deg,
                                                   float* __restrict__ dinv, int n) {
    int i = blockIdx.x * blockDim.x + threadIdx.x;
    if (i < n) dinv[i] = rsqrtf((float)(deg[i] + 1));
}

// ---------------------------------------------------------------------------
// Edge-parallel aggregation, D=128 (32 lanes per edge, float4 per lane).
// Items [0,E) are real edges; items [E, E+N) are self-loops (s=d=e-E).
__global__ __launch_bounds__(256) void aggregate128(
        const float* __restrict__ h, const int* __restrict__ src,
        const int* __restrict__ dst, const float* __restrict__ dinv,
        float* __restrict__ out, int E, int total) {
    int lane = threadIdx.x & 31;
    int item = (blockIdx.x * blockDim.x + threadIdx.x) >> 5;
    if (item >= total) return;
    int s, d;
    if (item < E) { s = src[item]; d = dst[item]; }
    else          { s = item - E; d = s; }
    float norm = dinv[s] * dinv[d];
    float4 v = ((const float4*)(h + (size_t)s * D_IN))[lane];
    float* op = out + (size_t)d * D_IN + lane * 4;
    atomicAdd(op + 0, norm * v.x);
    atomicAdd(op + 1, norm * v.y);
    atomicAdd(op + 2, norm * v.z);
    atomicAdd(op + 3, norm * v.w);
}

// ---------------------------------------------------------------------------
// Tiled fp32 GEMM: C[M,N] = A[M,K] @ B[K,N]; optional fused bias+ReLU.
// Block = 256 threads, 64x64 output tile, BK=64, 4x4 per-thread micro-tile.
template<bool BIAS_RELU>
__global__ __launch_bounds__(256) void gemm_tile(
        const float* __restrict__ A, const float* __restrict__ B,
        const float* __restrict__ bias, float* __restrict__ C,
        int M, int N, int K) {
    __shared__ float As[64][65];  // As[k][m], pad 65: conflict-free scalar reads
    __shared__ float Bs[64][68];  // Bs[k][n], pad 68: 16B-aligned float4 reads
    const int bm = blockIdx.x * 64;
    const int bn = blockIdx.y * 64;
    const int tid = threadIdx.x;
    const int tr = tid >> 4, tc = tid & 15;
    float acc[4][4] = {};
    for (int k0 = 0; k0 < K; k0 += 64) {
        for (int i = tid; i < 64 * 64; i += 256) {
            int r = i >> 6, c = i & 63;      // r = m-in-tile, c = k-in-tile
            int gr = bm + r;
            As[c][r] = (gr < M) ? A[(size_t)gr * K + k0 + c] : 0.0f;
        }
        for (int i = tid; i < 64 * 64; i += 256) {
            int r = i >> 6, c = i & 63;      // r = k-in-tile, c = n-in-tile
            Bs[r][c] = B[(size_t)(k0 + r) * N + bn + c];
        }
        __syncthreads();
        #pragma unroll 8
        for (int kk = 0; kk < 64; ++kk) {
            float a0 = As[kk][tr * 4 + 0];
            float a1 = As[kk][tr * 4 + 1];
            float a2 = As[kk][tr * 4 + 2];
            float a3 = As[kk][tr * 4 + 3];
            float4 b = *(const float4*)&Bs[kk][tc * 4];
            float av[4] = {a0, a1, a2, a3};
            float bv[4] = {b.x, b.y, b.z, b.w};
            #pragma unroll
            for (int i = 0; i < 4; ++i)
                #pragma unroll
                for (int j = 0; j < 4; ++j)
                    acc[i][j] += av[i] * bv[j];
        }
        __syncthreads();
    }
    #pragma unroll
    for (int i = 0; i < 4; ++i) {
        int gr = bm + tr * 4 + i;
        if (gr >= M) continue;
        float o[4];
        #pragma unroll
        for (int j = 0; j < 4; ++j) {
            float x = acc[i][j];
            if (BIAS_RELU) { x += bias[bn + tc * 4 + j]; x = fmaxf(x, 0.0f); }
            o[j] = x;
        }
        *(float4*)&C[(size_t)gr * N + bn + tc * 4] =
            make_float4(o[0], o[1], o[2], o[3]);
    }
}

// out[i, d] += b[d]   (D = 128)
__global__ __launch_bounds__(256) void bias_add128(float* __restrict__ out,
                                                   const float* __restrict__ b,
                                                   int total) {
    int i = blockIdx.x * blockDim.x + threadIdx.x;
    if (i < total) out[i] += b[i & (D_IN - 1)];
}

// ---------------------------------------------------------------------------
extern "C" void kernel_launch(void* const* d_in, const int* in_sizes, int n_in,
                              void* d_out, int out_size, void* d_ws, size_t ws_size,
                              hipStream_t stream) {
    const float* x  = (const float*)d_in[0];
    const int*   ei = (const int*)d_in[1];          // [2, E] int32
    const float* W1 = (const float*)d_in[2];
    const float* b1 = (const float*)d_in[3];
    const float* W2 = (const float*)d_in[4];
    const float* b2 = (const float*)d_in[5];
    const int* src = ei;
    const int* dst = ei + N_EDGES;
    float* out = (float*)d_out;

    // Workspace carve-up (all 256B-aligned)
    char* ws = (char*)d_ws;
    size_t off = 0;
    auto carve = [&](size_t bytes) {
        char* p = ws + off;
        off += (bytes + 255) & ~size_t(255);
        return p;
    };
    int*   deg  = (int*)  carve(N_NODES * sizeof(int));
    float* dinv = (float*)carve(N_NODES * sizeof(float));
    float* aggx = (float*)carve((size_t)N_NODES * D_IN  * sizeof(float));
    float* h1   = (float*)carve((size_t)N_NODES * D_HID * sizeof(float));
    float* t2   = (float*)carve((size_t)N_NODES * D_IN  * sizeof(float));
    (void)ws_size;

    // 1. degree + dinv
    hipMemsetAsync(deg, 0, N_NODES * sizeof(int), stream);
    deg_kernel<<<(N_EDGES + 255) / 256, 256, 0, stream>>>(dst, deg, N_EDGES);
    dinv_kernel<<<(N_NODES + 255) / 256, 256, 0, stream>>>(deg, dinv, N_NODES);

    // 2. agg_x = S @ x   (S = normalized adjacency incl. self-loops)
    hipMemsetAsync(aggx, 0, (size_t)N_NODES * D_IN * sizeof(float), stream);
    {
        int total = N_EDGES + N_NODES;
        long long threads = (long long)total * 32;
        int blocks = (int)((threads + 255) / 256);
        aggregate128<<<blocks, 256, 0, stream>>>(x, src, dst, dinv, aggx,
                                                 N_EDGES, total);
    }

    // 3. h1 = relu(agg_x @ W1 + b1)     [N, 256]
    {
        dim3 grid((N_NODES + 63) / 64, D_HID / 64);
        gemm_tile<true><<<grid, 256, 0, stream>>>(aggx, W1, b1, h1,
                                                  N_NODES, D_HID, D_IN);
    }

    // 4. t2 = h1 @ W2                   [N, 128]
    {
        dim3 grid((N_NODES + 63) / 64, D_IN / 64);
        gemm_tile<false><<<grid, 256, 0, stream>>>(h1, W2, nullptr, t2,
                                                   N_NODES, D_IN, D_HID);
    }

    // 5. out = S @ t2
    hipMemsetAsync(out, 0, (size_t)N_NODES * D_IN * sizeof(float), stream);
    {
        int total = N_EDGES + N_NODES;
        long long threads = (long long)total * 32;
        int blocks = (int)((threads + 255) / 256);
        aggregate128<<<blocks, 256, 0, stream>>>(t2, src, dst, dinv, out,
                                                 N_EDGES, total);
    }

    // 6. out += b2
    bias_add128<<<((N_NODES * D_IN) + 255) / 256, 256, 0, stream>>>(
        out, b2, N_NODES * D_IN);
}

// Round 2
// 726.627 us; speedup vs baseline: 8.0364x; 8.0364x over previous
//
#include <hip/hip_runtime.h>

#define N_NODES 50000
#define N_EDGES 1600000
#define D_IN 128
#define D_HID 256

#define SCAN_BLOCK 256
#define SCAN_ELEMS 2048                    // per block (256 threads x 8)
#define SCAN_GRID ((N_NODES + SCAN_ELEMS - 1) / SCAN_ELEMS)   // 25

// ---------------------------------------------------------------------------
// deg[i] = # real edges with dst == i
__global__ __launch_bounds__(256) void deg_kernel(const int* __restrict__ dst,
                                                  int* __restrict__ deg, int E) {
    int i = blockIdx.x * blockDim.x + threadIdx.x;
    int stride = gridDim.x * blockDim.x;
    for (; i < E; i += stride) atomicAdd(&deg[dst[i]], 1);
}

// dinv[i] = rsqrt(deg[i] + 1)   (+1 = self loop)
__global__ __launch_bounds__(256) void dinv_kernel(const int* __restrict__ deg,
                                                   float* __restrict__ dinv, int n) {
    int i = blockIdx.x * blockDim.x + threadIdx.x;
    if (i < n) dinv[i] = rsqrtf((float)(deg[i] + 1));
}

// ---------------------------------------------------------------------------
// 3-kernel exclusive scan of deg -> rowptr (block-local pass)
__global__ __launch_bounds__(SCAN_BLOCK) void scan1(const int* __restrict__ deg,
                                                    int* __restrict__ rowptr,
                                                    int* __restrict__ blocksums,
                                                    int n) {
    __shared__ int sm[SCAN_BLOCK];
    int base = blockIdx.x * SCAN_ELEMS + threadIdx.x * 8;
    int v[8];
    int tsum = 0;
    #pragma unroll
    for (int k = 0; k < 8; ++k) {
        int idx = base + k;
        v[k] = (idx < n) ? deg[idx] : 0;
        tsum += v[k];
    }
    sm[threadIdx.x] = tsum;
    __syncthreads();
    // Hillis-Steele inclusive scan over 256 thread sums
    for (int off = 1; off < SCAN_BLOCK; off <<= 1) {
        int add = (threadIdx.x >= off) ? sm[threadIdx.x - off] : 0;
        __syncthreads();
        sm[threadIdx.x] += add;
        __syncthreads();
    }
    int ex = sm[threadIdx.x] - tsum;   // exclusive base for this thread
    #pragma unroll
    for (int k = 0; k < 8; ++k) {
        int idx = base + k;
        if (idx < n) rowptr[idx] = ex;
        ex += v[k];
    }
    if (threadIdx.x == SCAN_BLOCK - 1) blocksums[blockIdx.x] = sm[threadIdx.x];
}

__global__ void scan2(int* __restrict__ blocksums, int g) {
    if (threadIdx.x == 0 && blockIdx.x == 0) {
        int run = 0;
        for (int i = 0; i < g; ++i) { int t = blocksums[i]; blocksums[i] = run; run += t; }
    }
}

// add block offsets; also init cursor = rowptr
__global__ __launch_bounds__(SCAN_BLOCK) void scan3(int* __restrict__ rowptr,
                                                    int* __restrict__ cursor,
                                                    const int* __restrict__ blocksums,
                                                    int n) {
    int base = blockIdx.x * SCAN_ELEMS + threadIdx.x * 8;
    int boff = blocksums[blockIdx.x];
    #pragma unroll
    for (int k = 0; k < 8; ++k) {
        int idx = base + k;
        if (idx < n) {
            int r = rowptr[idx] + boff;
            rowptr[idx] = r;
            cursor[idx] = r;
        }
    }
}

// counting-sort scatter: edata[pos] = { src, bits(dinv[s]*dinv[d]) }
__global__ __launch_bounds__(256) void scatter_kernel(
        const int* __restrict__ src, const int* __restrict__ dst,
        const float* __restrict__ dinv, int* __restrict__ cursor,
        int2* __restrict__ edata, int E) {
    int i = blockIdx.x * blockDim.x + threadIdx.x;
    int stride = gridDim.x * blockDim.x;
    for (; i < E; i += stride) {
        int s = src[i], d = dst[i];
        int pos = atomicAdd(&cursor[d], 1);
        float w = dinv[s] * dinv[d];
        edata[pos] = make_int2(s, __float_as_int(w));
    }
}

// ---------------------------------------------------------------------------
// Gather aggregation: one 64-lane wave per node, float2 per lane (D=128).
// out[n] = dinv[n]^2 * h[n] + sum_j w_j * h[src_j]  (+ bias if ADD_BIAS)
template<bool ADD_BIAS>
__global__ __launch_bounds__(256) void gather_agg(
        const float* __restrict__ h, const int2* __restrict__ edata,
        const int* __restrict__ rowptr, const int* __restrict__ deg,
        const float* __restrict__ dinv, const float* __restrict__ bias,
        float* __restrict__ out, int n) {
    int lane = threadIdx.x & 63;
    int node = blockIdx.x * 4 + (threadIdx.x >> 6);
    if (node >= n) return;
    int start = rowptr[node];
    int cnt = deg[node];
    float dn = dinv[node];
    float2 hv = ((const float2*)(h + (size_t)node * D_IN))[lane];
    float2 acc;
    acc.x = dn * dn * hv.x;
    acc.y = dn * dn * hv.y;
    for (int j = 0; j < cnt; ++j) {
        int2 ew = edata[start + j];
        float w = __int_as_float(ew.y);
        float2 v = ((const float2*)(h + (size_t)ew.x * D_IN))[lane];
        acc.x += w * v.x;
        acc.y += w * v.y;
    }
    if (ADD_BIAS) {
        float2 b = ((const float2*)bias)[lane];
        acc.x += b.x;
        acc.y += b.y;
    }
    ((float2*)(out + (size_t)node * D_IN))[lane] = acc;
}

// ---------------------------------------------------------------------------
// Tiled fp32 GEMM: C[M,N] = A[M,K] @ B[K,N]; optional fused bias+ReLU.
template<bool BIAS_RELU>
__global__ __launch_bounds__(256) void gemm_tile(
        const float* __restrict__ A, const float* __restrict__ B,
        const float* __restrict__ bias, float* __restrict__ C,
        int M, int N, int K) {
    __shared__ float As[64][65];
    __shared__ float Bs[64][68];
    const int bm = blockIdx.x * 64;
    const int bn = blockIdx.y * 64;
    const int tid = threadIdx.x;
    const int tr = tid >> 4, tc = tid & 15;
    float acc[4][4] = {};
    for (int k0 = 0; k0 < K; k0 += 64) {
        for (int i = tid; i < 64 * 64; i += 256) {
            int r = i >> 6, c = i & 63;
            int gr = bm + r;
            As[c][r] = (gr < M) ? A[(size_t)gr * K + k0 + c] : 0.0f;
        }
        for (int i = tid; i < 64 * 64; i += 256) {
            int r = i >> 6, c = i & 63;
            Bs[r][c] = B[(size_t)(k0 + r) * N + bn + c];
        }
        __syncthreads();
        #pragma unroll 8
        for (int kk = 0; kk < 64; ++kk) {
            float av[4] = {As[kk][tr * 4 + 0], As[kk][tr * 4 + 1],
                           As[kk][tr * 4 + 2], As[kk][tr * 4 + 3]};
            float4 b = *(const float4*)&Bs[kk][tc * 4];
            float bv[4] = {b.x, b.y, b.z, b.w};
            #pragma unroll
            for (int i = 0; i < 4; ++i)
                #pragma unroll
                for (int j = 0; j < 4; ++j)
                    acc[i][j] += av[i] * bv[j];
        }
        __syncthreads();
    }
    #pragma unroll
    for (int i = 0; i < 4; ++i) {
        int gr = bm + tr * 4 + i;
        if (gr >= M) continue;
        float o[4];
        #pragma unroll
        for (int j = 0; j < 4; ++j) {
            float x = acc[i][j];
            if (BIAS_RELU) { x += bias[bn + tc * 4 + j]; x = fmaxf(x, 0.0f); }
            o[j] = x;
        }
        *(float4*)&C[(size_t)gr * N + bn + tc * 4] =
            make_float4(o[0], o[1], o[2], o[3]);
    }
}

// ---------------------------------------------------------------------------
extern "C" void kernel_launch(void* const* d_in, const int* in_sizes, int n_in,
                              void* d_out, int out_size, void* d_ws, size_t ws_size,
                              hipStream_t stream) {
    const float* x  = (const float*)d_in[0];
    const int*   ei = (const int*)d_in[1];          // [2, E] int32
    const float* W1 = (const float*)d_in[2];
    const float* b1 = (const float*)d_in[3];
    const float* W2 = (const float*)d_in[4];
    const float* b2 = (const float*)d_in[5];
    const int* src = ei;
    const int* dst = ei + N_EDGES;
    float* out = (float*)d_out;

    char* ws = (char*)d_ws;
    size_t off = 0;
    auto carve = [&](size_t bytes) {
        char* p = ws + off;
        off += (bytes + 255) & ~size_t(255);
        return p;
    };
    int*   deg       = (int*)  carve(N_NODES * sizeof(int));
    int*   rowptr    = (int*)  carve(N_NODES * sizeof(int));
    int*   cursor    = (int*)  carve(N_NODES * sizeof(int));
    int*   blocksums = (int*)  carve(SCAN_GRID * sizeof(int));
    float* dinv      = (float*)carve(N_NODES * sizeof(float));
    int2*  edata     = (int2*) carve((size_t)N_EDGES * sizeof(int2));
    float* aggx      = (float*)carve((size_t)N_NODES * D_IN  * sizeof(float));
    float* h1        = (float*)carve((size_t)N_NODES * D_HID * sizeof(float));
    float* t2        = aggx;   // reuse: aggx dead after GEMM1
    (void)ws_size;

    // 1. CSR build: histogram -> dinv -> scan -> scatter
    hipMemsetAsync(deg, 0, N_NODES * sizeof(int), stream);
    deg_kernel<<<(N_EDGES + 255) / 256, 256, 0, stream>>>(dst, deg, N_EDGES);
    dinv_kernel<<<(N_NODES + 255) / 256, 256, 0, stream>>>(deg, dinv, N_NODES);
    scan1<<<SCAN_GRID, SCAN_BLOCK, 0, stream>>>(deg, rowptr, blocksums, N_NODES);
    scan2<<<1, 64, 0, stream>>>(blocksums, SCAN_GRID);
    scan3<<<SCAN_GRID, SCAN_BLOCK, 0, stream>>>(rowptr, cursor, blocksums, N_NODES);
    scatter_kernel<<<(N_EDGES + 255) / 256, 256, 0, stream>>>(
        src, dst, dinv, cursor, edata, N_EDGES);

    // 2. agg_x = S @ x
    gather_agg<false><<<(N_NODES + 3) / 4, 256, 0, stream>>>(
        x, edata, rowptr, deg, dinv, nullptr, aggx, N_NODES);

    // 3. h1 = relu(agg_x @ W1 + b1)
    {
        dim3 grid((N_NODES + 63) / 64, D_HID / 64);
        gemm_tile<true><<<grid, 256, 0, stream>>>(aggx, W1, b1, h1,
                                                  N_NODES, D_HID, D_IN);
    }

    // 4. t2 = h1 @ W2   (t2 aliases aggx; GEMM reads h1 only)
    {
        dim3 grid((N_NODES + 63) / 64, D_IN / 64);
        gemm_tile<false><<<grid, 256, 0, stream>>>(h1, W2, nullptr, t2,
                                                   N_NODES, D_IN, D_HID);
    }

    // 5. out = S @ t2 + b2   (bias fused)
    gather_agg<true><<<(N_NODES + 3) / 4, 256, 0, stream>>>(
        t2, edata, rowptr, deg, dinv, b2, out, N_NODES);
}

// Round 3
// 513.925 us; speedup vs baseline: 11.3625x; 1.4139x over previous
//
#include <hip/hip_runtime.h>

#define N_NODES 50000
#define N_EDGES 1600000
#define D_IN 128
#define D_HID 256

#define SCAN_BLOCK 256
#define SCAN_ELEMS 2048
#define SCAN_GRID ((N_NODES + SCAN_ELEMS - 1) / SCAN_ELEMS)   // 25

// ---------------------------------------------------------------------------
__device__ inline unsigned int f2_to_bf16x2(float a, float b) {
    unsigned int ua = __float_as_uint(a);
    ua = (ua + 0x7FFFu + ((ua >> 16) & 1u)) >> 16;
    unsigned int ub = __float_as_uint(b);
    ub = (ub + 0x7FFFu + ((ub >> 16) & 1u)) >> 16;
    return ua | (ub << 16);
}
__device__ inline float2 bf16x2_to_f2(unsigned int p) {
    float2 r;
    r.x = __uint_as_float(p << 16);
    r.y = __uint_as_float(p & 0xFFFF0000u);
    return r;
}

// ---------------------------------------------------------------------------
__global__ __launch_bounds__(256) void deg_kernel(const int* __restrict__ dst,
                                                  int* __restrict__ deg, int E) {
    int i = blockIdx.x * blockDim.x + threadIdx.x;
    int stride = gridDim.x * blockDim.x;
    for (; i < E; i += stride) atomicAdd(&deg[dst[i]], 1);
}

__global__ __launch_bounds__(256) void dinv_kernel(const int* __restrict__ deg,
                                                   float* __restrict__ dinv, int n) {
    int i = blockIdx.x * blockDim.x + threadIdx.x;
    if (i < n) dinv[i] = rsqrtf((float)(deg[i] + 1));
}

// ---------------------------------------------------------------------------
__global__ __launch_bounds__(SCAN_BLOCK) void scan1(const int* __restrict__ deg,
                                                    int* __restrict__ rowptr,
                                                    int* __restrict__ blocksums,
                                                    int n) {
    __shared__ int sm[SCAN_BLOCK];
    int base = blockIdx.x * SCAN_ELEMS + threadIdx.x * 8;
    int v[8];
    int tsum = 0;
    #pragma unroll
    for (int k = 0; k < 8; ++k) {
        int idx = base + k;
        v[k] = (idx < n) ? deg[idx] : 0;
        tsum += v[k];
    }
    sm[threadIdx.x] = tsum;
    __syncthreads();
    for (int off = 1; off < SCAN_BLOCK; off <<= 1) {
        int add = (threadIdx.x >= off) ? sm[threadIdx.x - off] : 0;
        __syncthreads();
        sm[threadIdx.x] += add;
        __syncthreads();
    }
    int ex = sm[threadIdx.x] - tsum;
    #pragma unroll
    for (int k = 0; k < 8; ++k) {
        int idx = base + k;
        if (idx < n) rowptr[idx] = ex;
        ex += v[k];
    }
    if (threadIdx.x == SCAN_BLOCK - 1) blocksums[blockIdx.x] = sm[threadIdx.x];
}

__global__ void scan2(int* __restrict__ blocksums, int g) {
    if (threadIdx.x == 0 && blockIdx.x == 0) {
        int run = 0;
        for (int i = 0; i < g; ++i) { int t = blocksums[i]; blocksums[i] = run; run += t; }
    }
}

__global__ __launch_bounds__(SCAN_BLOCK) void scan3(int* __restrict__ rowptr,
                                                    int* __restrict__ cursor,
                                                    const int* __restrict__ blocksums,
                                                    int n) {
    int base = blockIdx.x * SCAN_ELEMS + threadIdx.x * 8;
    int boff = blocksums[blockIdx.x];
    #pragma unroll
    for (int k = 0; k < 8; ++k) {
        int idx = base + k;
        if (idx < n) {
            int r = rowptr[idx] + boff;
            rowptr[idx] = r;
            cursor[idx] = r;
        }
    }
}

__global__ __launch_bounds__(256) void scatter_kernel(
        const int* __restrict__ src, const int* __restrict__ dst,
        const float* __restrict__ dinv, int* __restrict__ cursor,
        int2* __restrict__ edata, int E) {
    int i = blockIdx.x * blockDim.x + threadIdx.x;
    int stride = gridDim.x * blockDim.x;
    for (; i < E; i += stride) {
        int s = src[i], d = dst[i];
        int pos = atomicAdd(&cursor[d], 1);
        float w = dinv[s] * dinv[d];
        edata[pos] = make_int2(s, __float_as_int(w));
    }
}

// ---------------------------------------------------------------------------
// f32 -> packed bf16x2 (processes 4 floats / thread)
__global__ __launch_bounds__(256) void cvt_bf16(const float4* __restrict__ in,
                                                uint2* __restrict__ out, int n4) {
    int i = blockIdx.x * blockDim.x + threadIdx.x;
    if (i < n4) {
        float4 v = in[i];
        out[i] = make_uint2(f2_to_bf16x2(v.x, v.y), f2_to_bf16x2(v.z, v.w));
    }
}

// ---------------------------------------------------------------------------
// Gather aggregation, bf16 rows, fp32 accumulate. One 64-lane wave per node.
// Edge records for up to 64 edges are loaded coalesced then shfl-broadcast,
// so the row loads are independent -> 8-deep MLP.
template<bool ADD_BIAS>
__global__ __launch_bounds__(256) void gather_agg_bf16(
        const unsigned int* __restrict__ hb,   // [N, 64] packed bf16x2
        const int2* __restrict__ edata,
        const int* __restrict__ rowptr, const int* __restrict__ deg,
        const float* __restrict__ dinv, const float* __restrict__ bias,
        float* __restrict__ out, int n) {
    int lane = threadIdx.x & 63;
    int node = blockIdx.x * 4 + (threadIdx.x >> 6);
    if (node >= n) return;
    int start = rowptr[node];
    int cnt = deg[node];
    float dn = dinv[node];
    float2 hv = bf16x2_to_f2(hb[(size_t)node * 64 + lane]);
    float2 acc = make_float2(dn * dn * hv.x, dn * dn * hv.y);
    for (int c0 = 0; c0 < cnt; c0 += 64) {
        int m = min(64, cnt - c0);
        int2 ew = (lane < m) ? edata[start + c0 + lane] : make_int2(0, 0);
        int mr = (m + 7) & ~7;
        for (int j = 0; j < mr; j += 8) {
            float2 vv[8];
            float ww[8];
            #pragma unroll
            for (int k = 0; k < 8; ++k) {
                int sj = __shfl(ew.x, j + k);            // 0 for OOB lanes
                ww[k] = __int_as_float(__shfl(ew.y, j + k));  // 0.0f for OOB
                vv[k] = bf16x2_to_f2(hb[(size_t)sj * 64 + lane]);
            }
            #pragma unroll
            for (int k = 0; k < 8; ++k) {
                acc.x += ww[k] * vv[k].x;
                acc.y += ww[k] * vv[k].y;
            }
        }
    }
    if (ADD_BIAS) {
        float2 b = ((const float2*)bias)[lane];
        acc.x += b.x;
        acc.y += b.y;
    }
    ((float2*)(out + (size_t)node * D_IN))[lane] = acc;
}

// ---------------------------------------------------------------------------
// Tiled fp32 GEMM. MODE: 0 = plain fp32 out, 1 = bias+ReLU fp32 out,
//                        2 = packed-bf16 out (no bias).
template<int MODE>
__global__ __launch_bounds__(256) void gemm_tile(
        const float* __restrict__ A, const float* __restrict__ B,
        const float* __restrict__ bias, void* __restrict__ C,
        int M, int N, int K) {
    __shared__ float As[64][65];
    __shared__ float Bs[64][68];
    const int bm = blockIdx.x * 64;
    const int bn = blockIdx.y * 64;
    const int tid = threadIdx.x;
    const int tr = tid >> 4, tc = tid & 15;
    float acc[4][4] = {};
    for (int k0 = 0; k0 < K; k0 += 64) {
        for (int i = tid; i < 64 * 64; i += 256) {
            int r = i >> 6, c = i & 63;
            int gr = bm + r;
            As[c][r] = (gr < M) ? A[(size_t)gr * K + k0 + c] : 0.0f;
        }
        for (int i = tid; i < 64 * 64; i += 256) {
            int r = i >> 6, c = i & 63;
            Bs[r][c] = B[(size_t)(k0 + r) * N + bn + c];
        }
        __syncthreads();
        #pragma unroll 8
        for (int kk = 0; kk < 64; ++kk) {
            float av[4] = {As[kk][tr * 4 + 0], As[kk][tr * 4 + 1],
                           As[kk][tr * 4 + 2], As[kk][tr * 4 + 3]};
            float4 b = *(const float4*)&Bs[kk][tc * 4];
            float bv[4] = {b.x, b.y, b.z, b.w};
            #pragma unroll
            for (int i = 0; i < 4; ++i)
                #pragma unroll
                for (int j = 0; j < 4; ++j)
                    acc[i][j] += av[i] * bv[j];
        }
        __syncthreads();
    }
    #pragma unroll
    for (int i = 0; i < 4; ++i) {
        int gr = bm + tr * 4 + i;
        if (gr >= M) continue;
        float o[4];
        #pragma unroll
        for (int j = 0; j < 4; ++j) {
            float x = acc[i][j];
            if (MODE == 1) { x += bias[bn + tc * 4 + j]; x = fmaxf(x, 0.0f); }
            o[j] = x;
        }
        if (MODE == 2) {
            unsigned int* Cb = (unsigned int*)C;
            *(uint2*)&Cb[(size_t)gr * (N >> 1) + ((bn + tc * 4) >> 1)] =
                make_uint2(f2_to_bf16x2(o[0], o[1]), f2_to_bf16x2(o[2], o[3]));
        } else {
            *(float4*)&((float*)C)[(size_t)gr * N + bn + tc * 4] =
                make_float4(o[0], o[1], o[2], o[3]);
        }
    }
}

// ---------------------------------------------------------------------------
extern "C" void kernel_launch(void* const* d_in, const int* in_sizes, int n_in,
                              void* d_out, int out_size, void* d_ws, size_t ws_size,
                              hipStream_t stream) {
    const float* x  = (const float*)d_in[0];
    const int*   ei = (const int*)d_in[1];          // [2, E] int32
    const float* W1 = (const float*)d_in[2];
    const float* b1 = (const float*)d_in[3];
    const float* W2 = (const float*)d_in[4];
    const float* b2 = (const float*)d_in[5];
    const int* src = ei;
    const int* dst = ei + N_EDGES;
    float* out = (float*)d_out;

    char* ws = (char*)d_ws;
    size_t off = 0;
    auto carve = [&](size_t bytes) {
        char* p = ws + off;
        off += (bytes + 255) & ~size_t(255);
        return p;
    };
    int*   deg       = (int*)  carve(N_NODES * sizeof(int));
    int*   rowptr    = (int*)  carve(N_NODES * sizeof(int));
    int*   cursor    = (int*)  carve(N_NODES * sizeof(int));
    int*   blocksums = (int*)  carve(SCAN_GRID * sizeof(int));
    float* dinv      = (float*)carve(N_NODES * sizeof(float));
    int2*  edata     = (int2*) carve((size_t)N_EDGES * sizeof(int2));
    unsigned int* xb = (unsigned int*)carve((size_t)N_NODES * 64 * sizeof(unsigned int));
    float* aggx      = (float*)carve((size_t)N_NODES * D_IN  * sizeof(float));
    float* h1        = (float*)carve((size_t)N_NODES * D_HID * sizeof(float));
    unsigned int* t2b = xb;   // reuse: xb dead after gather1
    (void)ws_size;

    // 1. CSR build
    hipMemsetAsync(deg, 0, N_NODES * sizeof(int), stream);
    deg_kernel<<<(N_EDGES + 255) / 256, 256, 0, stream>>>(dst, deg, N_EDGES);
    dinv_kernel<<<(N_NODES + 255) / 256, 256, 0, stream>>>(deg, dinv, N_NODES);
    scan1<<<SCAN_GRID, SCAN_BLOCK, 0, stream>>>(deg, rowptr, blocksums, N_NODES);
    scan2<<<1, 64, 0, stream>>>(blocksums, SCAN_GRID);
    scan3<<<SCAN_GRID, SCAN_BLOCK, 0, stream>>>(rowptr, cursor, blocksums, N_NODES);
    scatter_kernel<<<(N_EDGES + 255) / 256, 256, 0, stream>>>(
        src, dst, dinv, cursor, edata, N_EDGES);

    // 2. x -> bf16
    cvt_bf16<<<(N_NODES * D_IN / 4 + 255) / 256, 256, 0, stream>>>(
        (const float4*)x, (uint2*)xb, N_NODES * D_IN / 4);

    // 3. agg_x = S @ x          (bf16 gather, fp32 accum)
    gather_agg_bf16<false><<<(N_NODES + 3) / 4, 256, 0, stream>>>(
        xb, edata, rowptr, deg, dinv, nullptr, aggx, N_NODES);

    // 4. h1 = relu(agg_x @ W1 + b1)
    {
        dim3 grid((N_NODES + 63) / 64, D_HID / 64);
        gemm_tile<1><<<grid, 256, 0, stream>>>(aggx, W1, b1, (void*)h1,
                                               N_NODES, D_HID, D_IN);
    }

    // 5. t2b = bf16(h1 @ W2)    (t2b aliases xb — xb dead after step 3)
    {
        dim3 grid((N_NODES + 63) / 64, D_IN / 64);
        gemm_tile<2><<<grid, 256, 0, stream>>>(h1, W2, nullptr, (void*)t2b,
                                               N_NODES, D_IN, D_HID);
    }

    // 6. out = S @ t2 + b2
    gather_agg_bf16<true><<<(N_NODES + 3) / 4, 256, 0, stream>>>(
        t2b, edata, rowptr, deg, dinv, b2, out, N_NODES);
}

// Round 4
// 425.145 us; speedup vs baseline: 13.7353x; 1.2088x over previous
//
#include <hip/hip_runtime.h>

#define N_NODES 50000
#define N_EDGES 1600000
#define D_IN 128
#define D_HID 256

#define SCAN_BLOCK 256
#define SCAN_ELEMS 2048
#define SCAN_GRID ((N_NODES + SCAN_ELEMS - 1) / SCAN_ELEMS)   // 25

typedef short bh8 __attribute__((ext_vector_type(8)));   // 8 bf16 (4 VGPRs)
typedef float f32x4 __attribute__((ext_vector_type(4))); // MFMA C/D

// ---------------------------------------------------------------------------
__device__ inline unsigned int f2_to_bf16x2(float a, float b) {
    unsigned int ua = __float_as_uint(a);
    ua = (ua + 0x7FFFu + ((ua >> 16) & 1u)) >> 16;
    unsigned int ub = __float_as_uint(b);
    ub = (ub + 0x7FFFu + ((ub >> 16) & 1u)) >> 16;
    return ua | (ub << 16);
}
__device__ inline unsigned short f_to_bf16(float a) {
    unsigned int ua = __float_as_uint(a);
    return (unsigned short)((ua + 0x7FFFu + ((ua >> 16) & 1u)) >> 16);
}
__device__ inline float2 bf16x2_to_f2(unsigned int p) {
    float2 r;
    r.x = __uint_as_float(p << 16);
    r.y = __uint_as_float(p & 0xFFFF0000u);
    return r;
}

// ---------------------------------------------------------------------------
__global__ __launch_bounds__(256) void deg_kernel(const int* __restrict__ dst,
                                                  int* __restrict__ deg, int E) {
    int i = blockIdx.x * blockDim.x + threadIdx.x;
    int stride = gridDim.x * blockDim.x;
    for (; i < E; i += stride) atomicAdd(&deg[dst[i]], 1);
}

__global__ __launch_bounds__(256) void dinv_kernel(const int* __restrict__ deg,
                                                   float* __restrict__ dinv, int n) {
    int i = blockIdx.x * blockDim.x + threadIdx.x;
    if (i < n) dinv[i] = rsqrtf((float)(deg[i] + 1));
}

// ---------------------------------------------------------------------------
__global__ __launch_bounds__(SCAN_BLOCK) void scan1(const int* __restrict__ deg,
                                                    int* __restrict__ rowptr,
                                                    int* __restrict__ blocksums,
                                                    int n) {
    __shared__ int sm[SCAN_BLOCK];
    int base = blockIdx.x * SCAN_ELEMS + threadIdx.x * 8;
    int v[8];
    int tsum = 0;
    #pragma unroll
    for (int k = 0; k < 8; ++k) {
        int idx = base + k;
        v[k] = (idx < n) ? deg[idx] : 0;
        tsum += v[k];
    }
    sm[threadIdx.x] = tsum;
    __syncthreads();
    for (int off = 1; off < SCAN_BLOCK; off <<= 1) {
        int add = (threadIdx.x >= off) ? sm[threadIdx.x - off] : 0;
        __syncthreads();
        sm[threadIdx.x] += add;
        __syncthreads();
    }
    int ex = sm[threadIdx.x] - tsum;
    #pragma unroll
    for (int k = 0; k < 8; ++k) {
        int idx = base + k;
        if (idx < n) rowptr[idx] = ex;
        ex += v[k];
    }
    if (threadIdx.x == SCAN_BLOCK - 1) blocksums[blockIdx.x] = sm[threadIdx.x];
}

__global__ void scan2(int* __restrict__ blocksums, int g) {
    if (threadIdx.x == 0 && blockIdx.x == 0) {
        int run = 0;
        for (int i = 0; i < g; ++i) { int t = blocksums[i]; blocksums[i] = run; run += t; }
    }
}

__global__ __launch_bounds__(SCAN_BLOCK) void scan3(int* __restrict__ rowptr,
                                                    int* __restrict__ cursor,
                                                    const int* __restrict__ blocksums,
                                                    int n) {
    int base = blockIdx.x * SCAN_ELEMS + threadIdx.x * 8;
    int boff = blocksums[blockIdx.x];
    #pragma unroll
    for (int k = 0; k < 8; ++k) {
        int idx = base + k;
        if (idx < n) {
            int r = rowptr[idx] + boff;
            rowptr[idx] = r;
            cursor[idx] = r;
        }
    }
}

__global__ __launch_bounds__(256) void scatter_kernel(
        const int* __restrict__ src, const int* __restrict__ dst,
        const float* __restrict__ dinv, int* __restrict__ cursor,
        int2* __restrict__ edata, int E) {
    int i = blockIdx.x * blockDim.x + threadIdx.x;
    int stride = gridDim.x * blockDim.x;
    for (; i < E; i += stride) {
        int s = src[i], d = dst[i];
        int pos = atomicAdd(&cursor[d], 1);
        float w = dinv[s] * dinv[d];
        edata[pos] = make_int2(s, __float_as_int(w));
    }
}

// ---------------------------------------------------------------------------
// f32 -> packed bf16x2 (4 floats / thread)
__global__ __launch_bounds__(256) void cvt_bf16(const float4* __restrict__ in,
                                                uint2* __restrict__ out, int n4) {
    int i = blockIdx.x * blockDim.x + threadIdx.x;
    if (i < n4) {
        float4 v = in[i];
        out[i] = make_uint2(f2_to_bf16x2(v.x, v.y), f2_to_bf16x2(v.z, v.w));
    }
}

// W[k][n] fp32 -> WT[n][k] bf16  (writes coalesced; reads strided but tiny)
__global__ __launch_bounds__(256) void cvtT_w(const float* __restrict__ W,
                                              unsigned short* __restrict__ WT,
                                              int K, int N) {
    int t = blockIdx.x * blockDim.x + threadIdx.x;
    if (t >= K * N) return;
    int n = t / K, k = t - n * K;
    WT[t] = f_to_bf16(W[(size_t)k * N + n]);
}

// ---------------------------------------------------------------------------
// Gather aggregation, bf16 rows, fp32 accumulate. One 64-lane wave per node.
// OUT_BF16: write packed bf16 (no bias). Else: fp32 out + bias.
template<bool OUT_BF16>
__global__ __launch_bounds__(256) void gather_agg_bf16(
        const unsigned int* __restrict__ hb,   // [N, 64] packed bf16x2
        const int2* __restrict__ edata,
        const int* __restrict__ rowptr, const int* __restrict__ deg,
        const float* __restrict__ dinv, const float* __restrict__ bias,
        void* __restrict__ out, int n) {
    int lane = threadIdx.x & 63;
    int node = blockIdx.x * 4 + (threadIdx.x >> 6);
    if (node >= n) return;
    int start = rowptr[node];
    int cnt = deg[node];
    float dn = dinv[node];
    float2 hv = bf16x2_to_f2(hb[(size_t)node * 64 + lane]);
    float2 acc = make_float2(dn * dn * hv.x, dn * dn * hv.y);
    for (int c0 = 0; c0 < cnt; c0 += 64) {
        int m = min(64, cnt - c0);
        int2 ew = (lane < m) ? edata[start + c0 + lane] : make_int2(0, 0);
        int mr = (m + 7) & ~7;
        for (int j = 0; j < mr; j += 8) {
            float2 vv[8];
            float ww[8];
            #pragma unroll
            for (int k = 0; k < 8; ++k) {
                int sj = __shfl(ew.x, j + k);
                ww[k] = __int_as_float(__shfl(ew.y, j + k));
                vv[k] = bf16x2_to_f2(hb[(size_t)sj * 64 + lane]);
            }
            #pragma unroll
            for (int k = 0; k < 8; ++k) {
                acc.x += ww[k] * vv[k].x;
                acc.y += ww[k] * vv[k].y;
            }
        }
    }
    if (OUT_BF16) {
        ((unsigned int*)out)[(size_t)node * 64 + lane] = f2_to_bf16x2(acc.x, acc.y);
    } else {
        float2 b = ((const float2*)bias)[lane];
        acc.x += b.x;
        acc.y += b.y;
        ((float2*)((float*)out + (size_t)node * D_IN))[lane] = acc;
    }
}

// ---------------------------------------------------------------------------
// MFMA bf16 GEMM: C[M,N] = A[M,K] @ W[K,N], A/W/C all bf16 (fp32 accum).
// WT = W pre-transposed [N][K]. Block: 128 M-rows, 4 waves split N.
// MODE 1: fused bias+ReLU. MODE 2: plain.
template<int N, int K, int MODE>
__global__ __launch_bounds__(256) void gemm_mfma(
        const unsigned short* __restrict__ WT,  // [N][K] bf16
        const unsigned int* __restrict__ Ab,    // [M][K/2] packed bf16
        const float* __restrict__ bias,
        unsigned short* __restrict__ Cb,        // [M][N] bf16
        int M) {
    constexpr int KP = K + 8;                   // padded row (16B-aligned, odd dw/2)
    constexpr int KSTEPS = K / 32;
    constexpr int TPW = N / 64;                 // n-tiles per wave (GEMM1:4, GEMM2:2)
    __shared__ unsigned short Bs[N * KP];

    const int tid = threadIdx.x;
    // stage WT -> Bs, 16B chunks, coalesced
    for (int c = tid; c < N * (K / 8); c += 256) {
        int nn = c / (K / 8), kc = c - nn * (K / 8);
        uint4 v = ((const uint4*)(WT + (size_t)nn * K))[kc];
        *(uint4*)&Bs[nn * KP + kc * 8] = v;
    }
    __syncthreads();

    const int wave = tid >> 6, lane = tid & 63;
    const int n0 = wave * (TPW * 16);
    const int m_base = blockIdx.x * 128;
    const int rit = lane & 15;                  // row-in-tile / col-in-tile
    const int kg = lane >> 4;                   // k-group 0..3

    f32x4 acc[8][TPW];
    #pragma unroll
    for (int rg = 0; rg < 8; ++rg)
        #pragma unroll
        for (int t = 0; t < TPW; ++t)
            acc[rg][t] = (f32x4){0.f, 0.f, 0.f, 0.f};

    bh8 a0[8], a1[8];
    #define LOAD_A(KS, DST)                                                  \
        _Pragma("unroll")                                                    \
        for (int rg = 0; rg < 8; ++rg) {                                     \
            int m = m_base + rg * 16 + rit;                                  \
            m = min(m, M - 1);                                               \
            DST[rg] = *(const bh8*)(Ab + (size_t)m * (K / 2) + (KS)*16 + kg * 4); \
        }

    LOAD_A(0, a0)
    #pragma unroll
    for (int ks = 0; ks < KSTEPS; ++ks) {
        if (ks + 1 < KSTEPS) {
            if ((ks & 1) == 0) { LOAD_A(ks + 1, a1) }
            else               { LOAD_A(ks + 1, a0) }
        }
        #pragma unroll
        for (int t = 0; t < TPW; ++t) {
            bh8 b = *(const bh8*)&Bs[(n0 + t * 16 + rit) * KP + ks * 32 + kg * 8];
            #pragma unroll
            for (int rg = 0; rg < 8; ++rg) {
                bh8 a = ((ks & 1) == 0) ? a0[rg] : a1[rg];
                acc[rg][t] = __builtin_amdgcn_mfma_f32_16x16x32_bf16(
                    a, b, acc[rg][t], 0, 0, 0);
            }
        }
    }
    #undef LOAD_A

    // epilogue: C/D layout col=lane&15, row=(lane>>4)*4+i  [m89]
    #pragma unroll
    for (int t = 0; t < TPW; ++t) {
        int col = n0 + t * 16 + rit;
        float bv = (MODE == 1) ? bias[col] : 0.0f;
        #pragma unroll
        for (int rg = 0; rg < 8; ++rg) {
            #pragma unroll
            for (int i = 0; i < 4; ++i) {
                int m = m_base + rg * 16 + kg * 4 + i;
                float v = acc[rg][t][i];
                if (MODE == 1) { v += bv; v = fmaxf(v, 0.0f); }
                if (m < M) Cb[(size_t)m * N + col] = f_to_bf16(v);
            }
        }
    }
}

// ---------------------------------------------------------------------------
extern "C" void kernel_launch(void* const* d_in, const int* in_sizes, int n_in,
                              void* d_out, int out_size, void* d_ws, size_t ws_size,
                              hipStream_t stream) {
    const float* x  = (const float*)d_in[0];
    const int*   ei = (const int*)d_in[1];          // [2, E] int32
    const float* W1 = (const float*)d_in[2];
    const float* b1 = (const float*)d_in[3];
    const float* W2 = (const float*)d_in[4];
    const float* b2 = (const float*)d_in[5];
    const int* src = ei;
    const int* dst = ei + N_EDGES;
    float* out = (float*)d_out;

    char* ws = (char*)d_ws;
    size_t off = 0;
    auto carve = [&](size_t bytes) {
        char* p = ws + off;
        off += (bytes + 255) & ~size_t(255);
        return p;
    };
    int*   deg       = (int*)  carve(N_NODES * sizeof(int));
    int*   rowptr    = (int*)  carve(N_NODES * sizeof(int));
    int*   cursor    = (int*)  carve(N_NODES * sizeof(int));
    int*   blocksums = (int*)  carve(SCAN_GRID * sizeof(int));
    float* dinv      = (float*)carve(N_NODES * sizeof(float));
    int2*  edata     = (int2*) carve((size_t)N_EDGES * sizeof(int2));
    unsigned int* xb   = (unsigned int*)carve((size_t)N_NODES * 64 * sizeof(unsigned int));
    unsigned int* aggb = (unsigned int*)carve((size_t)N_NODES * 64 * sizeof(unsigned int));
    unsigned int* h1b  = (unsigned int*)carve((size_t)N_NODES * 128 * sizeof(unsigned int));
    unsigned short* W1T = (unsigned short*)carve((size_t)D_IN * D_HID * sizeof(unsigned short));
    unsigned short* W2T = (unsigned short*)carve((size_t)D_HID * D_IN * sizeof(unsigned short));
    unsigned int* t2b = xb;   // reuse: xb dead after gather1
    (void)ws_size;

    // 1. CSR build
    hipMemsetAsync(deg, 0, N_NODES * sizeof(int), stream);
    deg_kernel<<<(N_EDGES + 255) / 256, 256, 0, stream>>>(dst, deg, N_EDGES);
    dinv_kernel<<<(N_NODES + 255) / 256, 256, 0, stream>>>(deg, dinv, N_NODES);
    scan1<<<SCAN_GRID, SCAN_BLOCK, 0, stream>>>(deg, rowptr, blocksums, N_NODES);
    scan2<<<1, 64, 0, stream>>>(blocksums, SCAN_GRID);
    scan3<<<SCAN_GRID, SCAN_BLOCK, 0, stream>>>(rowptr, cursor, blocksums, N_NODES);
    scatter_kernel<<<(N_EDGES + 255) / 256, 256, 0, stream>>>(
        src, dst, dinv, cursor, edata, N_EDGES);

    // 2. conversions: x -> bf16, W1/W2 -> transposed bf16
    cvt_bf16<<<(N_NODES * D_IN / 4 + 255) / 256, 256, 0, stream>>>(
        (const float4*)x, (uint2*)xb, N_NODES * D_IN / 4);
    cvtT_w<<<(D_IN * D_HID + 255) / 256, 256, 0, stream>>>(W1, W1T, D_IN, D_HID);
    cvtT_w<<<(D_HID * D_IN + 255) / 256, 256, 0, stream>>>(W2, W2T, D_HID, D_IN);

    // 3. aggb = bf16(S @ x)
    gather_agg_bf16<true><<<(N_NODES + 3) / 4, 256, 0, stream>>>(
        xb, edata, rowptr, deg, dinv, nullptr, (void*)aggb, N_NODES);

    // 4. h1b = bf16(relu(aggb @ W1 + b1))   [MFMA]
    gemm_mfma<D_HID, D_IN, 1><<<(N_NODES + 127) / 128, 256, 0, stream>>>(
        W1T, aggb, b1, (unsigned short*)h1b, N_NODES);

    // 5. t2b = bf16(h1b @ W2)               [MFMA]
    gemm_mfma<D_IN, D_HID, 2><<<(N_NODES + 127) / 128, 256, 0, stream>>>(
        W2T, h1b, nullptr, (unsigned short*)t2b, N_NODES);

    // 6. out = S @ t2 + b2
    gather_agg_bf16<false><<<(N_NODES + 3) / 4, 256, 0, stream>>>(
        t2b, edata, rowptr, deg, dinv, b2, (void*)out, N_NODES);
}